// Round 1
// baseline (442.860 us; speedup 1.0000x reference)
//
#include <hip/hip_runtime.h>
#include <stdint.h>

// B=2, S=2048, D_MODEL=768, H=12, HD=64, 7*D=5376
typedef short short8 __attribute__((ext_vector_type(8)));
typedef float f32x4 __attribute__((ext_vector_type(4)));
typedef unsigned short u16x4 __attribute__((ext_vector_type(4)));

#define MFMA16 __builtin_amdgcn_mfma_f32_16x16x32_bf16

__device__ __forceinline__ unsigned short f2bf(float f) {
  union { float f; unsigned u; } v; v.f = f;
  return (unsigned short)((v.u + 0x7FFFu + ((v.u >> 16) & 1u)) >> 16);
}

// ---------------- convert f32 -> bf16, 4 elems/thread ----------------
__global__ __launch_bounds__(256) void cvt_bf16_4(const float* __restrict__ in,
                                                  unsigned short* __restrict__ out,
                                                  int n) {
  int i = (blockIdx.x * 256 + threadIdx.x) * 4;
  if (i >= n) return;
  f32x4 v = *(const f32x4*)(in + i);
  u16x4 o;
  o.x = f2bf(v.x); o.y = f2bf(v.y); o.z = f2bf(v.z); o.w = f2bf(v.w);
  *(u16x4*)(out + i) = o;
}

// ---------------- GEMM: C[M][N] = A[M][K] * B[N][K]^T + bias ----------------
// 128x128 tile, BK=64, 256 threads (4 waves as 2x2 of 64x64).
// LDS tiles XOR-swizzled: LDS[row][j] holds global chunk (j ^ (row&7)), chunk=16B.
template <bool OUT_BF16>
__global__ __launch_bounds__(256) void gemm_nt(const unsigned short* __restrict__ A,
                                               const unsigned short* __restrict__ Bm,
                                               const float* __restrict__ bias,
                                               void* __restrict__ Cout,
                                               int M, int N, int K) {
  __shared__ __align__(16) char smem[32768];
  char* As = smem;            // [128][64] bf16, swizzled
  char* Bs = smem + 16384;    // [128][64] bf16, swizzled
  const int tid = threadIdx.x;
  const int w = tid >> 6, l = tid & 63;
  const int wm = w >> 1, wn = w & 1;
  const int Row0 = blockIdx.y * 128, Col0 = blockIdx.x * 128;

  f32x4 z; z.x = 0.f; z.y = 0.f; z.z = 0.f; z.w = 0.f;
  f32x4 acc[4][4];
  for (int m = 0; m < 4; ++m)
    for (int n = 0; n < 4; ++n) acc[m][n] = z;

  for (int k0 = 0; k0 < K; k0 += 64) {
    for (int it = 0; it < 4; ++it) {
      int slot = it * 256 + tid;          // 1024 slots of 16B per tile
      int row = slot >> 3, j = slot & 7;
      int gc = j ^ (row & 7);
      *(short8*)(As + row * 128 + j * 16) =
          *(const short8*)(A + (size_t)(Row0 + row) * K + k0 + gc * 8);
      *(short8*)(Bs + row * 128 + j * 16) =
          *(const short8*)(Bm + (size_t)(Col0 + row) * K + k0 + gc * 8);
    }
    __syncthreads();
    for (int kc = 0; kc < 2; ++kc) {
      int c = (l >> 4) + 4 * kc;
      short8 af[4], bf[4];
      for (int m = 0; m < 4; ++m) {
        int t = wm * 64 + m * 16 + (l & 15);
        af[m] = *(const short8*)(As + t * 128 + ((c ^ (t & 7)) * 16));
      }
      for (int n = 0; n < 4; ++n) {
        int t = wn * 64 + n * 16 + (l & 15);
        bf[n] = *(const short8*)(Bs + t * 128 + ((c ^ (t & 7)) * 16));
      }
      for (int m = 0; m < 4; ++m)
        for (int n = 0; n < 4; ++n)
          acc[m][n] = MFMA16(af[m], bf[n], acc[m][n], 0, 0, 0);
    }
    __syncthreads();
  }
  for (int n = 0; n < 4; ++n) {
    int col = Col0 + wn * 64 + n * 16 + (l & 15);
    float bv = bias[col];
    for (int m = 0; m < 4; ++m) {
      int rbase = Row0 + wm * 64 + m * 16 + (l >> 4) * 4;
      for (int r = 0; r < 4; ++r) {
        float v = acc[m][n][r] + bv;
        size_t idx = (size_t)(rbase + r) * N + col;
        if (OUT_BF16) ((unsigned short*)Cout)[idx] = f2bf(v);
        else          ((float*)Cout)[idx] = v;
      }
    }
  }
}

// ---------------- pass1: t1 = a1@v, t2 = a2@v, u = silu(t1)*t2 ----------------
// grid (24 = b*12+h, 32 t-tiles of 64). 256 thr = 4 waves x 16 t-rows.
__global__ __launch_bounds__(256) void pass1(const unsigned short* __restrict__ qkv,
                                             unsigned short* __restrict__ u) {
  __shared__ __align__(16) char smem[40960];
  char* K1s = smem;           // [64 s][64 d] bf16 swizzled
  char* K2s = smem + 8192;
  char* Vt  = smem + 16384;   // [64 d][64 s] bf16 swizzled (transposed V)
  char* A1s = smem + 24576;   // 4 waves x [16 t][64 s] bf16 swizzled
  char* A2s = smem + 32768;
  const int tid = threadIdx.x, w = tid >> 6, l = tid & 63;
  const int b = blockIdx.x / 12, h = blockIdx.x % 12;
  const int tt = blockIdx.y;

  // preload Q1/Q2 fragments (A-operand): row = l&15, k contiguous
  const int tg = tt * 64 + w * 16 + (l & 15);
  const size_t qbase = (size_t)(b * 2048 + tg) * 5376 + h * 64;
  short8 q1f[2], q2f[2];
  for (int kc = 0; kc < 2; ++kc) {
    int d = kc * 32 + (l >> 4) * 8;
    q1f[kc] = *(const short8*)(qkv + qbase + 0 * 768 + d);
    q2f[kc] = *(const short8*)(qkv + qbase + 2 * 768 + d);
  }

  f32x4 z; z.x = 0.f; z.y = 0.f; z.z = 0.f; z.w = 0.f;
  f32x4 t1a[4], t2a[4];
  for (int n = 0; n < 4; ++n) { t1a[n] = z; t2a[n] = z; }

  for (int s0 = 0; s0 < 2048; s0 += 64) {
    // stage K1, K2 (row-major swizzled) and V transposed
    for (int it = 0; it < 2; ++it) {
      int slot = it * 256 + tid;          // 512 slots
      int row = slot >> 3, j = slot & 7;
      int gc = j ^ (row & 7);
      size_t srow = (size_t)(b * 2048 + s0 + row) * 5376 + h * 64;
      *(short8*)(K1s + row * 128 + j * 16) = *(const short8*)(qkv + srow + 1 * 768 + gc * 8);
      *(short8*)(K2s + row * 128 + j * 16) = *(const short8*)(qkv + srow + 3 * 768 + gc * 8);
      short8 v8 = *(const short8*)(qkv + srow + 6 * 768 + j * 8);
      for (int e = 0; e < 8; ++e) {
        int d = j * 8 + e, s = row;
        *(unsigned short*)(Vt + d * 128 + (((s >> 3) ^ (d & 7)) * 16) + (s & 7) * 2) =
            (unsigned short)v8[e];
      }
    }
    __syncthreads();

    // scores: a1,a2 = Q K^T  (16 t-rows x 64 s-cols per wave)
    f32x4 a1[4], a2[4];
    for (int n = 0; n < 4; ++n) { a1[n] = z; a2[n] = z; }
    for (int kc = 0; kc < 2; ++kc) {
      int c = (l >> 4) + 4 * kc;
      for (int n = 0; n < 4; ++n) {
        int srw = n * 16 + (l & 15);
        short8 k1f = *(const short8*)(K1s + srw * 128 + ((c ^ (srw & 7)) * 16));
        short8 k2f = *(const short8*)(K2s + srw * 128 + ((c ^ (srw & 7)) * 16));
        a1[n] = MFMA16(q1f[kc], k1f, a1[n], 0, 0, 0);
        a2[n] = MFMA16(q2f[kc], k2f, a2[n], 0, 0, 0);
      }
    }

    // write scores to per-wave LDS (bf16) to re-fragment for PV
    char* myA1 = A1s + w * 2048;
    char* myA2 = A2s + w * 2048;
    for (int n = 0; n < 4; ++n)
      for (int r = 0; r < 4; ++r) {
        int trow = (l >> 4) * 4 + r;
        int scol = n * 16 + (l & 15);
        int byte = trow * 128 + (((scol >> 3) ^ (trow & 7)) * 16) + (scol & 7) * 2;
        *(unsigned short*)(myA1 + byte) = f2bf(a1[n][r]);
        *(unsigned short*)(myA2 + byte) = f2bf(a2[n][r]);
      }
    __syncthreads();

    // PV: t1 += a1 @ V, t2 += a2 @ V  (k = s)
    for (int kc = 0; kc < 2; ++kc) {
      int trow = l & 15;
      int c = (l >> 4) + 4 * kc;
      short8 p1 = *(const short8*)(myA1 + trow * 128 + ((c ^ (trow & 7)) * 16));
      short8 p2 = *(const short8*)(myA2 + trow * 128 + ((c ^ (trow & 7)) * 16));
      for (int n = 0; n < 4; ++n) {
        int drow = n * 16 + (l & 15);
        short8 vf = *(const short8*)(Vt + drow * 128 + ((c ^ (drow & 7)) * 16));
        t1a[n] = MFMA16(p1, vf, t1a[n], 0, 0, 0);
        t2a[n] = MFMA16(p2, vf, t2a[n], 0, 0, 0);
      }
    }
    __syncthreads();
  }

  // u = silu(t1) * t2, store bf16 [b][t][h*64+d]
  for (int n = 0; n < 4; ++n)
    for (int r = 0; r < 4; ++r) {
      int t = tt * 64 + w * 16 + (l >> 4) * 4 + r;
      int d = n * 16 + (l & 15);
      float x1 = t1a[n][r], x2 = t2a[n][r];
      float uu = (x1 / (1.f + expf(-x1))) * x2;
      u[(size_t)(b * 2048 + t) * 768 + h * 64 + d] = f2bf(uu);
    }
}

// ---------------- pass2: ctx = a3 @ u ----------------
__global__ __launch_bounds__(256) void pass2(const unsigned short* __restrict__ qkv,
                                             const unsigned short* __restrict__ u,
                                             float* __restrict__ ctx) {
  __shared__ __align__(16) char smem[24576];
  char* K3s = smem;           // [64 s][64 d]
  char* Ut  = smem + 8192;    // [64 d][64 s] transposed u
  char* A3s = smem + 16384;   // 4 x [16][64]
  const int tid = threadIdx.x, w = tid >> 6, l = tid & 63;
  const int b = blockIdx.x / 12, h = blockIdx.x % 12;
  const int tt = blockIdx.y;

  const int tg = tt * 64 + w * 16 + (l & 15);
  const size_t qbase = (size_t)(b * 2048 + tg) * 5376 + h * 64;
  short8 q3f[2];
  for (int kc = 0; kc < 2; ++kc)
    q3f[kc] = *(const short8*)(qkv + qbase + 4 * 768 + kc * 32 + (l >> 4) * 8);

  f32x4 z; z.x = 0.f; z.y = 0.f; z.z = 0.f; z.w = 0.f;
  f32x4 ca[4];
  for (int n = 0; n < 4; ++n) ca[n] = z;

  for (int s0 = 0; s0 < 2048; s0 += 64) {
    for (int it = 0; it < 2; ++it) {
      int slot = it * 256 + tid;
      int row = slot >> 3, j = slot & 7;
      int gc = j ^ (row & 7);
      size_t srow = (size_t)(b * 2048 + s0 + row) * 5376 + h * 64;
      *(short8*)(K3s + row * 128 + j * 16) = *(const short8*)(qkv + srow + 5 * 768 + gc * 8);
      short8 u8 = *(const short8*)(u + (size_t)(b * 2048 + s0 + row) * 768 + h * 64 + j * 8);
      for (int e = 0; e < 8; ++e) {
        int d = j * 8 + e, s = row;
        *(unsigned short*)(Ut + d * 128 + (((s >> 3) ^ (d & 7)) * 16) + (s & 7) * 2) =
            (unsigned short)u8[e];
      }
    }
    __syncthreads();

    f32x4 a3[4];
    for (int n = 0; n < 4; ++n) a3[n] = z;
    for (int kc = 0; kc < 2; ++kc) {
      int c = (l >> 4) + 4 * kc;
      for (int n = 0; n < 4; ++n) {
        int srw = n * 16 + (l & 15);
        short8 kf = *(const short8*)(K3s + srw * 128 + ((c ^ (srw & 7)) * 16));
        a3[n] = MFMA16(q3f[kc], kf, a3[n], 0, 0, 0);
      }
    }
    char* myA = A3s + w * 2048;
    for (int n = 0; n < 4; ++n)
      for (int r = 0; r < 4; ++r) {
        int trow = (l >> 4) * 4 + r;
        int scol = n * 16 + (l & 15);
        int byte = trow * 128 + (((scol >> 3) ^ (trow & 7)) * 16) + (scol & 7) * 2;
        *(unsigned short*)(myA + byte) = f2bf(a3[n][r]);
      }
    __syncthreads();

    for (int kc = 0; kc < 2; ++kc) {
      int trow = l & 15;
      int c = (l >> 4) + 4 * kc;
      short8 p3 = *(const short8*)(myA + trow * 128 + ((c ^ (trow & 7)) * 16));
      for (int n = 0; n < 4; ++n) {
        int drow = n * 16 + (l & 15);
        short8 uf = *(const short8*)(Ut + drow * 128 + ((c ^ (drow & 7)) * 16));
        ca[n] = MFMA16(p3, uf, ca[n], 0, 0, 0);
      }
    }
    __syncthreads();
  }

  for (int n = 0; n < 4; ++n)
    for (int r = 0; r < 4; ++r) {
      int t = tt * 64 + w * 16 + (l >> 4) * 4 + r;
      int d = n * 16 + (l & 15);
      ctx[(size_t)(b * 2048 + t) * 768 + h * 64 + d] = ca[n][r];
    }
}

// ---------------- GroupNorm stats: 24 groups (b,h), over S x HD ----------------
__global__ __launch_bounds__(256) void gn_stats(const float* __restrict__ ctx,
                                                float* __restrict__ stats) {
  const int g = blockIdx.x;          // 0..23
  const int b = g / 12, h = g % 12;
  double s = 0.0, s2 = 0.0;
  for (int i = threadIdx.x; i < 2048 * 64; i += 256) {
    int t = i >> 6, d = i & 63;
    float v = ctx[(size_t)(b * 2048 + t) * 768 + h * 64 + d];
    s += v; s2 += (double)v * (double)v;
  }
  __shared__ double red0[256];
  __shared__ double red1[256];
  red0[threadIdx.x] = s; red1[threadIdx.x] = s2;
  __syncthreads();
  for (int st = 128; st > 0; st >>= 1) {
    if (threadIdx.x < st) {
      red0[threadIdx.x] += red0[threadIdx.x + st];
      red1[threadIdx.x] += red1[threadIdx.x + st];
    }
    __syncthreads();
  }
  if (threadIdx.x == 0) {
    const double N = 2048.0 * 64.0;
    double mean = red0[0] / N;
    double var = red1[0] / N - mean * mean;
    stats[g * 2] = (float)mean;
    stats[g * 2 + 1] = (float)(1.0 / sqrt(var + 1e-5));
  }
}

// ---------------- normalize + affine -> bf16 ----------------
__global__ __launch_bounds__(256) void gn_apply(const float* __restrict__ ctx,
                                                const float* __restrict__ stats,
                                                const float* __restrict__ gw,
                                                const float* __restrict__ gb,
                                                unsigned short* __restrict__ outc) {
  int i = blockIdx.x * 256 + threadIdx.x;
  if (i >= 4096 * 768) return;
  int c = i % 768;
  int b = i / (2048 * 768);
  int g = b * 12 + (c >> 6);
  float v = (ctx[i] - stats[2 * g]) * stats[2 * g + 1];
  outc[i] = f2bf(v * gw[c] + gb[c]);
}

extern "C" void kernel_launch(void* const* d_in, const int* in_sizes, int n_in,
                              void* d_out, int out_size, void* d_ws, size_t ws_size,
                              hipStream_t stream) {
  const float* x   = (const float*)d_in[0];
  const float* Wpw = (const float*)d_in[1];
  const float* Wpb = (const float*)d_in[2];
  const float* gnw = (const float*)d_in[3];
  const float* gnb = (const float*)d_in[4];
  const float* ow  = (const float*)d_in[5];
  const float* ob  = (const float*)d_in[6];
  float* out = (float*)d_out;

  char* ws = (char*)d_ws;
  size_t off = 0;
  auto carve = [&](size_t bytes) {
    char* p = ws + off;
    off = (off + bytes + 255) & ~(size_t)255;
    return p;
  };
  unsigned short* xb   = (unsigned short*)carve((size_t)4096 * 768 * 2);   // x bf16; reused as ctxn
  unsigned short* wb   = (unsigned short*)carve((size_t)5376 * 768 * 2);   // Wproj bf16
  unsigned short* owb  = (unsigned short*)carve((size_t)768 * 768 * 2);    // out_w bf16
  unsigned short* qkvb = (unsigned short*)carve((size_t)4096 * 5376 * 2);  // qkv bf16
  unsigned short* ub   = (unsigned short*)carve((size_t)4096 * 768 * 2);   // u bf16
  float* ctx           = (float*)carve((size_t)4096 * 768 * 4);            // ctx f32
  float* stats         = (float*)carve(48 * 4);                            // mean/rstd x24

  cvt_bf16_4<<<3072, 256, 0, stream>>>(x, xb, 4096 * 768);
  cvt_bf16_4<<<4032, 256, 0, stream>>>(Wpw, wb, 5376 * 768);
  cvt_bf16_4<<<576, 256, 0, stream>>>(ow, owb, 768 * 768);

  gemm_nt<true><<<dim3(42, 32), 256, 0, stream>>>(xb, wb, Wpb, qkvb, 4096, 5376, 768);
  pass1<<<dim3(24, 32), 256, 0, stream>>>(qkvb, ub);
  pass2<<<dim3(24, 32), 256, 0, stream>>>(qkvb, ub, ctx);
  gn_stats<<<24, 256, 0, stream>>>(ctx, stats);
  gn_apply<<<12288, 256, 0, stream>>>(ctx, stats, gnw, gnb, xb);  // xb reused as ctxn
  gemm_nt<false><<<dim3(6, 32), 256, 0, stream>>>(xb, owb, ob, out, 4096, 768, 768);
}

// Round 2
// 309.269 us; speedup vs baseline: 1.4320x; 1.4320x over previous
//
#include <hip/hip_runtime.h>
#include <stdint.h>

// B=2, S=2048, D_MODEL=768, H=12, HD=64, 7*D=5376
typedef short short8 __attribute__((ext_vector_type(8)));
typedef float f32x4 __attribute__((ext_vector_type(4)));
typedef unsigned short u16x4 __attribute__((ext_vector_type(4)));

#define MFMA16 __builtin_amdgcn_mfma_f32_16x16x32_bf16

__device__ __forceinline__ unsigned short f2bf(float f) {
  union { float f; unsigned u; } v; v.f = f;
  return (unsigned short)((v.u + 0x7FFFu + ((v.u >> 16) & 1u)) >> 16);
}

// ---------------- convert f32 -> bf16, 4 elems/thread ----------------
__global__ __launch_bounds__(256) void cvt_bf16_4(const float* __restrict__ in,
                                                  unsigned short* __restrict__ out,
                                                  int n) {
  int i = (blockIdx.x * 256 + threadIdx.x) * 4;
  if (i >= n) return;
  f32x4 v = *(const f32x4*)(in + i);
  u16x4 o;
  o.x = f2bf(v.x); o.y = f2bf(v.y); o.z = f2bf(v.z); o.w = f2bf(v.w);
  *(u16x4*)(out + i) = o;
}

// ---------------- GEMM: C[M][N] = A[M][K] * B[N][K]^T + bias ----------------
// 128x128 tile, BK=64, 256 threads (4 waves as 2x2 of 64x64).
// LDS tiles XOR-swizzled: LDS[row][j] holds global chunk (j ^ (row&7)), chunk=16B.
template <bool OUT_BF16>
__global__ __launch_bounds__(256) void gemm_nt(const unsigned short* __restrict__ A,
                                               const unsigned short* __restrict__ Bm,
                                               const float* __restrict__ bias,
                                               void* __restrict__ Cout,
                                               int M, int N, int K) {
  __shared__ __align__(16) char smem[32768];
  char* As = smem;            // [128][64] bf16, swizzled
  char* Bs = smem + 16384;    // [128][64] bf16, swizzled
  const int tid = threadIdx.x;
  const int w = tid >> 6, l = tid & 63;
  const int wm = w >> 1, wn = w & 1;
  const int Row0 = blockIdx.y * 128, Col0 = blockIdx.x * 128;

  f32x4 z; z.x = 0.f; z.y = 0.f; z.z = 0.f; z.w = 0.f;
  f32x4 acc[4][4];
  for (int m = 0; m < 4; ++m)
    for (int n = 0; n < 4; ++n) acc[m][n] = z;

  for (int k0 = 0; k0 < K; k0 += 64) {
    for (int it = 0; it < 4; ++it) {
      int slot = it * 256 + tid;          // 1024 slots of 16B per tile
      int row = slot >> 3, j = slot & 7;
      int gc = j ^ (row & 7);
      *(short8*)(As + row * 128 + j * 16) =
          *(const short8*)(A + (size_t)(Row0 + row) * K + k0 + gc * 8);
      *(short8*)(Bs + row * 128 + j * 16) =
          *(const short8*)(Bm + (size_t)(Col0 + row) * K + k0 + gc * 8);
    }
    __syncthreads();
    for (int kc = 0; kc < 2; ++kc) {
      int c = (l >> 4) + 4 * kc;
      short8 af[4], bf[4];
      for (int m = 0; m < 4; ++m) {
        int t = wm * 64 + m * 16 + (l & 15);
        af[m] = *(const short8*)(As + t * 128 + ((c ^ (t & 7)) * 16));
      }
      for (int n = 0; n < 4; ++n) {
        int t = wn * 64 + n * 16 + (l & 15);
        bf[n] = *(const short8*)(Bs + t * 128 + ((c ^ (t & 7)) * 16));
      }
      for (int m = 0; m < 4; ++m)
        for (int n = 0; n < 4; ++n)
          acc[m][n] = MFMA16(af[m], bf[n], acc[m][n], 0, 0, 0);
    }
    __syncthreads();
  }
  for (int n = 0; n < 4; ++n) {
    int col = Col0 + wn * 64 + n * 16 + (l & 15);
    float bv = bias[col];
    for (int m = 0; m < 4; ++m) {
      int rbase = Row0 + wm * 64 + m * 16 + (l >> 4) * 4;
      for (int r = 0; r < 4; ++r) {
        float v = acc[m][n][r] + bv;
        size_t idx = (size_t)(rbase + r) * N + col;
        if (OUT_BF16) ((unsigned short*)Cout)[idx] = f2bf(v);
        else          ((float*)Cout)[idx] = v;
      }
    }
  }
}

// ---------------- pass1: t1 = a1@v, t2 = a2@v, u = silu(t1)*t2 ----------------
// grid (24 = b*12+h, 32 t-tiles of 64). 256 thr = 4 waves x 16 t-rows.
__global__ __launch_bounds__(256) void pass1(const unsigned short* __restrict__ qkv,
                                             unsigned short* __restrict__ u) {
  __shared__ __align__(16) char smem[40960];
  char* K1s = smem;           // [64 s][64 d] bf16 swizzled
  char* K2s = smem + 8192;
  char* Vt  = smem + 16384;   // [64 d][64 s] bf16 swizzled (transposed V)
  char* A1s = smem + 24576;   // 4 waves x [16 t][64 s] bf16 swizzled
  char* A2s = smem + 32768;
  const int tid = threadIdx.x, w = tid >> 6, l = tid & 63;
  const int b = blockIdx.x / 12, h = blockIdx.x % 12;
  const int tt = blockIdx.y;

  // preload Q1/Q2 fragments (A-operand): row = l&15, k contiguous
  const int tg = tt * 64 + w * 16 + (l & 15);
  const size_t qbase = (size_t)(b * 2048 + tg) * 5376 + h * 64;
  short8 q1f[2], q2f[2];
  for (int kc = 0; kc < 2; ++kc) {
    int d = kc * 32 + (l >> 4) * 8;
    q1f[kc] = *(const short8*)(qkv + qbase + 0 * 768 + d);
    q2f[kc] = *(const short8*)(qkv + qbase + 2 * 768 + d);
  }

  f32x4 z; z.x = 0.f; z.y = 0.f; z.z = 0.f; z.w = 0.f;
  f32x4 t1a[4], t2a[4];
  for (int n = 0; n < 4; ++n) { t1a[n] = z; t2a[n] = z; }

  for (int s0 = 0; s0 < 2048; s0 += 64) {
    // stage K1, K2 (row-major swizzled) and V transposed
    for (int it = 0; it < 2; ++it) {
      int slot = it * 256 + tid;          // 512 slots
      int row = slot >> 3, j = slot & 7;
      int gc = j ^ (row & 7);
      size_t srow = (size_t)(b * 2048 + s0 + row) * 5376 + h * 64;
      *(short8*)(K1s + row * 128 + j * 16) = *(const short8*)(qkv + srow + 1 * 768 + gc * 8);
      *(short8*)(K2s + row * 128 + j * 16) = *(const short8*)(qkv + srow + 3 * 768 + gc * 8);
      short8 v8 = *(const short8*)(qkv + srow + 6 * 768 + j * 8);
      for (int e = 0; e < 8; ++e) {
        int d = j * 8 + e, s = row;
        *(unsigned short*)(Vt + d * 128 + (((s >> 3) ^ (d & 7)) * 16) + (s & 7) * 2) =
            (unsigned short)v8[e];
      }
    }
    __syncthreads();

    // scores: a1,a2 = Q K^T  (16 t-rows x 64 s-cols per wave)
    f32x4 a1[4], a2[4];
    for (int n = 0; n < 4; ++n) { a1[n] = z; a2[n] = z; }
    for (int kc = 0; kc < 2; ++kc) {
      int c = (l >> 4) + 4 * kc;
      for (int n = 0; n < 4; ++n) {
        int srw = n * 16 + (l & 15);
        short8 k1f = *(const short8*)(K1s + srw * 128 + ((c ^ (srw & 7)) * 16));
        short8 k2f = *(const short8*)(K2s + srw * 128 + ((c ^ (srw & 7)) * 16));
        a1[n] = MFMA16(q1f[kc], k1f, a1[n], 0, 0, 0);
        a2[n] = MFMA16(q2f[kc], k2f, a2[n], 0, 0, 0);
      }
    }

    // write scores to per-wave LDS (bf16) to re-fragment for PV
    char* myA1 = A1s + w * 2048;
    char* myA2 = A2s + w * 2048;
    for (int n = 0; n < 4; ++n)
      for (int r = 0; r < 4; ++r) {
        int trow = (l >> 4) * 4 + r;
        int scol = n * 16 + (l & 15);
        int byte = trow * 128 + (((scol >> 3) ^ (trow & 7)) * 16) + (scol & 7) * 2;
        *(unsigned short*)(myA1 + byte) = f2bf(a1[n][r]);
        *(unsigned short*)(myA2 + byte) = f2bf(a2[n][r]);
      }
    __syncthreads();

    // PV: t1 += a1 @ V, t2 += a2 @ V  (k = s)
    for (int kc = 0; kc < 2; ++kc) {
      int trow = l & 15;
      int c = (l >> 4) + 4 * kc;
      short8 p1 = *(const short8*)(myA1 + trow * 128 + ((c ^ (trow & 7)) * 16));
      short8 p2 = *(const short8*)(myA2 + trow * 128 + ((c ^ (trow & 7)) * 16));
      for (int n = 0; n < 4; ++n) {
        int drow = n * 16 + (l & 15);
        short8 vf = *(const short8*)(Vt + drow * 128 + ((c ^ (drow & 7)) * 16));
        t1a[n] = MFMA16(p1, vf, t1a[n], 0, 0, 0);
        t2a[n] = MFMA16(p2, vf, t2a[n], 0, 0, 0);
      }
    }
    __syncthreads();
  }

  // u = silu(t1) * t2, store bf16 [b][t][h*64+d]
  for (int n = 0; n < 4; ++n)
    for (int r = 0; r < 4; ++r) {
      int t = tt * 64 + w * 16 + (l >> 4) * 4 + r;
      int d = n * 16 + (l & 15);
      float x1 = t1a[n][r], x2 = t2a[n][r];
      float uu = (x1 / (1.f + expf(-x1))) * x2;
      u[(size_t)(b * 2048 + t) * 768 + h * 64 + d] = f2bf(uu);
    }
}

// ---------------- pass2: ctx = a3 @ u, + per-block GN partial sums ----------------
__global__ __launch_bounds__(256) void pass2(const unsigned short* __restrict__ qkv,
                                             const unsigned short* __restrict__ u,
                                             float* __restrict__ ctx,
                                             float* __restrict__ partials) {
  __shared__ __align__(16) char smem[24576];
  char* K3s = smem;           // [64 s][64 d]
  char* Ut  = smem + 8192;    // [64 d][64 s] transposed u
  char* A3s = smem + 16384;   // 4 x [16][64]
  const int tid = threadIdx.x, w = tid >> 6, l = tid & 63;
  const int b = blockIdx.x / 12, h = blockIdx.x % 12;
  const int tt = blockIdx.y;

  const int tg = tt * 64 + w * 16 + (l & 15);
  const size_t qbase = (size_t)(b * 2048 + tg) * 5376 + h * 64;
  short8 q3f[2];
  for (int kc = 0; kc < 2; ++kc)
    q3f[kc] = *(const short8*)(qkv + qbase + 4 * 768 + kc * 32 + (l >> 4) * 8);

  f32x4 z; z.x = 0.f; z.y = 0.f; z.z = 0.f; z.w = 0.f;
  f32x4 ca[4];
  for (int n = 0; n < 4; ++n) ca[n] = z;

  for (int s0 = 0; s0 < 2048; s0 += 64) {
    for (int it = 0; it < 2; ++it) {
      int slot = it * 256 + tid;
      int row = slot >> 3, j = slot & 7;
      int gc = j ^ (row & 7);
      size_t srow = (size_t)(b * 2048 + s0 + row) * 5376 + h * 64;
      *(short8*)(K3s + row * 128 + j * 16) = *(const short8*)(qkv + srow + 5 * 768 + gc * 8);
      short8 u8 = *(const short8*)(u + (size_t)(b * 2048 + s0 + row) * 768 + h * 64 + j * 8);
      for (int e = 0; e < 8; ++e) {
        int d = j * 8 + e, s = row;
        *(unsigned short*)(Ut + d * 128 + (((s >> 3) ^ (d & 7)) * 16) + (s & 7) * 2) =
            (unsigned short)u8[e];
      }
    }
    __syncthreads();

    f32x4 a3[4];
    for (int n = 0; n < 4; ++n) a3[n] = z;
    for (int kc = 0; kc < 2; ++kc) {
      int c = (l >> 4) + 4 * kc;
      for (int n = 0; n < 4; ++n) {
        int srw = n * 16 + (l & 15);
        short8 kf = *(const short8*)(K3s + srw * 128 + ((c ^ (srw & 7)) * 16));
        a3[n] = MFMA16(q3f[kc], kf, a3[n], 0, 0, 0);
      }
    }
    char* myA = A3s + w * 2048;
    for (int n = 0; n < 4; ++n)
      for (int r = 0; r < 4; ++r) {
        int trow = (l >> 4) * 4 + r;
        int scol = n * 16 + (l & 15);
        int byte = trow * 128 + (((scol >> 3) ^ (trow & 7)) * 16) + (scol & 7) * 2;
        *(unsigned short*)(myA + byte) = f2bf(a3[n][r]);
      }
    __syncthreads();

    for (int kc = 0; kc < 2; ++kc) {
      int trow = l & 15;
      int c = (l >> 4) + 4 * kc;
      short8 p3 = *(const short8*)(myA + trow * 128 + ((c ^ (trow & 7)) * 16));
      for (int n = 0; n < 4; ++n) {
        int drow = n * 16 + (l & 15);
        short8 uf = *(const short8*)(Ut + drow * 128 + ((c ^ (drow & 7)) * 16));
        ca[n] = MFMA16(p3, uf, ca[n], 0, 0, 0);
      }
    }
    __syncthreads();
  }

  float psum = 0.f, psum2 = 0.f;
  for (int n = 0; n < 4; ++n)
    for (int r = 0; r < 4; ++r) {
      int t = tt * 64 + w * 16 + (l >> 4) * 4 + r;
      int d = n * 16 + (l & 15);
      float v = ca[n][r];
      ctx[(size_t)(b * 2048 + t) * 768 + h * 64 + d] = v;
      psum += v; psum2 += v * v;
    }

  // block-level reduce of (sum, sumsq) -> partials[(g*32+tt)*2 .. +1]
  float* red = (float*)smem;                  // reuse LDS (done with tiles)
  red[tid] = psum; red[256 + tid] = psum2;
  __syncthreads();
  for (int st = 128; st > 0; st >>= 1) {
    if (tid < st) {
      red[tid] += red[tid + st];
      red[256 + tid] += red[256 + tid + st];
    }
    __syncthreads();
  }
  if (tid == 0) {
    int g = blockIdx.x;
    partials[(g * 32 + tt) * 2] = red[0];
    partials[(g * 32 + tt) * 2 + 1] = red[256];
  }
}

// ---------------- finalize GN stats from 32 partials per group ----------------
__global__ __launch_bounds__(64) void gn_finalize(const float* __restrict__ partials,
                                                  float* __restrict__ stats) {
  const int g = blockIdx.x;      // 0..23
  const int l = threadIdx.x;     // 0..63
  double s = 0.0, s2 = 0.0;
  if (l < 32) {
    s = (double)partials[(g * 32 + l) * 2];
    s2 = (double)partials[(g * 32 + l) * 2 + 1];
  }
  for (int off = 32; off > 0; off >>= 1) {
    s += __shfl_down(s, off, 64);
    s2 += __shfl_down(s2, off, 64);
  }
  if (l == 0) {
    const double N = 2048.0 * 64.0;
    double mean = s / N;
    double var = s2 / N - mean * mean;
    stats[g * 2] = (float)mean;
    stats[g * 2 + 1] = (float)(1.0 / sqrt(var + 1e-5));
  }
}

// ---------------- normalize + affine -> bf16 ----------------
__global__ __launch_bounds__(256) void gn_apply(const float* __restrict__ ctx,
                                                const float* __restrict__ stats,
                                                const float* __restrict__ gw,
                                                const float* __restrict__ gb,
                                                unsigned short* __restrict__ outc) {
  int i = blockIdx.x * 256 + threadIdx.x;
  if (i >= 4096 * 768) return;
  int c = i % 768;
  int b = i / (2048 * 768);
  int g = b * 12 + (c >> 6);
  float v = (ctx[i] - stats[2 * g]) * stats[2 * g + 1];
  outc[i] = f2bf(v * gw[c] + gb[c]);
}

extern "C" void kernel_launch(void* const* d_in, const int* in_sizes, int n_in,
                              void* d_out, int out_size, void* d_ws, size_t ws_size,
                              hipStream_t stream) {
  const float* x   = (const float*)d_in[0];
  const float* Wpw = (const float*)d_in[1];
  const float* Wpb = (const float*)d_in[2];
  const float* gnw = (const float*)d_in[3];
  const float* gnb = (const float*)d_in[4];
  const float* ow  = (const float*)d_in[5];
  const float* ob  = (const float*)d_in[6];
  float* out = (float*)d_out;

  char* ws = (char*)d_ws;
  size_t off = 0;
  auto carve = [&](size_t bytes) {
    char* p = ws + off;
    off = (off + bytes + 255) & ~(size_t)255;
    return p;
  };
  unsigned short* xb   = (unsigned short*)carve((size_t)4096 * 768 * 2);   // x bf16; reused as ctxn
  unsigned short* wb   = (unsigned short*)carve((size_t)5376 * 768 * 2);   // Wproj bf16
  unsigned short* owb  = (unsigned short*)carve((size_t)768 * 768 * 2);    // out_w bf16
  unsigned short* qkvb = (unsigned short*)carve((size_t)4096 * 5376 * 2);  // qkv bf16
  unsigned short* ub   = (unsigned short*)carve((size_t)4096 * 768 * 2);   // u bf16
  float* ctx           = (float*)carve((size_t)4096 * 768 * 4);            // ctx f32
  float* partials      = (float*)carve(24 * 32 * 2 * 4);                   // per-block GN sums
  float* stats         = (float*)carve(48 * 4);                            // mean/rstd x24

  cvt_bf16_4<<<3072, 256, 0, stream>>>(x, xb, 4096 * 768);
  cvt_bf16_4<<<4032, 256, 0, stream>>>(Wpw, wb, 5376 * 768);
  cvt_bf16_4<<<576, 256, 0, stream>>>(ow, owb, 768 * 768);

  gemm_nt<true><<<dim3(42, 32), 256, 0, stream>>>(xb, wb, Wpb, qkvb, 4096, 5376, 768);
  pass1<<<dim3(24, 32), 256, 0, stream>>>(qkvb, ub);
  pass2<<<dim3(24, 32), 256, 0, stream>>>(qkvb, ub, ctx, partials);
  gn_finalize<<<24, 64, 0, stream>>>(partials, stats);
  gn_apply<<<12288, 256, 0, stream>>>(ctx, stats, gnw, gnb, xb);  // xb reused as ctxn
  gemm_nt<false><<<dim3(6, 32), 256, 0, stream>>>(xb, owb, ob, out, 4096, 768, 768);
}

// Round 3
// 238.094 us; speedup vs baseline: 1.8600x; 1.2989x over previous
//
#include <hip/hip_runtime.h>
#include <hip/hip_bf16.h>
#include <stdint.h>

// B=2, S=2048, D_MODEL=768, H=12, HD=64, 7*D=5376
typedef short short8 __attribute__((ext_vector_type(8)));
typedef float f32x4 __attribute__((ext_vector_type(4)));
typedef unsigned short u16x4 __attribute__((ext_vector_type(4)));

#define MFMA16 __builtin_amdgcn_mfma_f32_16x16x32_bf16

typedef unsigned int __attribute__((address_space(1))) as1_u32;
typedef unsigned int __attribute__((address_space(3))) as3_u32;
// async global->LDS, 16B per lane; dest must be wave-uniform base + lane*16
#define GLOAD16(gsrc, ldst) \
  __builtin_amdgcn_global_load_lds((const as1_u32*)(gsrc), (as3_u32*)(ldst), 16, 0, 0)

__device__ __forceinline__ unsigned short f2bf(float f) {
  __hip_bfloat16 h = __float2bfloat16(f);   // HW RNE convert
  return *(unsigned short*)&h;
}

// ---------------- convert f32 -> bf16, 4 elems/thread ----------------
__global__ __launch_bounds__(256) void cvt_bf16_4(const float* __restrict__ in,
                                                  unsigned short* __restrict__ out,
                                                  int n) {
  int i = (blockIdx.x * 256 + threadIdx.x) * 4;
  if (i >= n) return;
  f32x4 v = *(const f32x4*)(in + i);
  u16x4 o;
  o.x = f2bf(v.x); o.y = f2bf(v.y); o.z = f2bf(v.z); o.w = f2bf(v.w);
  *(u16x4*)(out + i) = o;
}

// ---------------- 64x64 head-tile transpose: src[b][s][stride] -> dst[bh][d][2048] ----
// Conflict-free via rotation: phys s-slot = (s + 8*(d>>3)) & 63.
__global__ __launch_bounds__(256) void transp64(const unsigned short* __restrict__ src,
                                                int stride, int off,
                                                unsigned short* __restrict__ dst) {
  __shared__ __align__(16) unsigned short t[64 * 64];
  const int tid = threadIdx.x;
  const int tt = blockIdx.x, bh = blockIdx.y;
  const int b = bh / 12, h = bh % 12;
  const unsigned short* sbase = src + (size_t)(b * 2048 + tt * 64) * stride + h * 64 + off;
  for (int it = 0; it < 2; ++it) {
    int slot = it * 256 + tid, s = slot >> 3, j = slot & 7;
    short8 v = *(const short8*)(sbase + (size_t)s * stride + j * 8);
    int phys = (s + 8 * j) & 63;
    for (int e = 0; e < 8; ++e)
      t[(j * 8 + e) * 64 + phys] = ((unsigned short*)&v)[e];
  }
  __syncthreads();
  unsigned short* dbase = dst + (size_t)bh * 64 * 2048 + tt * 64;
  for (int it = 0; it < 2; ++it) {
    int slot = it * 256 + tid, d = slot >> 3, c = slot & 7;
    int pc = (c + (d >> 3)) & 7;
    short8 v = *(const short8*)(t + d * 64 + pc * 8);
    *(short8*)(dbase + (size_t)d * 2048 + c * 8) = v;
  }
}

// ---------------- GEMM: C[M][N] = A[M][K] * B[N][K]^T + bias ----------------
// 128x128 tile, BK=64, 256 threads; staging via global_load_lds (pre-swizzled src).
template <bool OUT_BF16>
__global__ __launch_bounds__(256) void gemm_nt(const unsigned short* __restrict__ A,
                                               const unsigned short* __restrict__ Bm,
                                               const float* __restrict__ bias,
                                               void* __restrict__ Cout,
                                               int M, int N, int K) {
  __shared__ __align__(16) char smem[32768];
  char* As = smem;            // [128][64] bf16, swizzled
  char* Bs = smem + 16384;    // [128][64] bf16, swizzled
  const int tid = threadIdx.x;
  const int w = tid >> 6, l = tid & 63;
  const int wm = w >> 1, wn = w & 1;
  const int Row0 = blockIdx.y * 128, Col0 = blockIdx.x * 128;

  f32x4 z; z.x = 0.f; z.y = 0.f; z.z = 0.f; z.w = 0.f;
  f32x4 acc[4][4];
  for (int m = 0; m < 4; ++m)
    for (int n = 0; n < 4; ++n) acc[m][n] = z;

  for (int k0 = 0; k0 < K; k0 += 64) {
    for (int it = 0; it < 4; ++it) {
      int slot = it * 256 + tid;          // 1024 slots of 16B per tile
      int row = slot >> 3, j = slot & 7;
      int gc = j ^ (row & 7);
      GLOAD16(A + (size_t)(Row0 + row) * K + k0 + gc * 8, As + slot * 16);
      GLOAD16(Bm + (size_t)(Col0 + row) * K + k0 + gc * 8, Bs + slot * 16);
    }
    __syncthreads();
    for (int kc = 0; kc < 2; ++kc) {
      int c = (l >> 4) + 4 * kc;
      short8 af[4], bf[4];
      for (int m = 0; m < 4; ++m) {
        int t = wm * 64 + m * 16 + (l & 15);
        af[m] = *(const short8*)(As + t * 128 + ((c ^ (t & 7)) * 16));
      }
      for (int n = 0; n < 4; ++n) {
        int t = wn * 64 + n * 16 + (l & 15);
        bf[n] = *(const short8*)(Bs + t * 128 + ((c ^ (t & 7)) * 16));
      }
      for (int m = 0; m < 4; ++m)
        for (int n = 0; n < 4; ++n)
          acc[m][n] = MFMA16(af[m], bf[n], acc[m][n], 0, 0, 0);
    }
    __syncthreads();
  }
  for (int n = 0; n < 4; ++n) {
    int col = Col0 + wn * 64 + n * 16 + (l & 15);
    float bv = bias[col];
    for (int m = 0; m < 4; ++m) {
      int rbase = Row0 + wm * 64 + m * 16 + (l >> 4) * 4;
      for (int r = 0; r < 4; ++r) {
        float v = acc[m][n][r] + bv;
        size_t idx = (size_t)(rbase + r) * N + col;
        if (OUT_BF16) ((unsigned short*)Cout)[idx] = f2bf(v);
        else          ((float*)Cout)[idx] = v;
      }
    }
  }
}

// ---------------- pass1: t1 = a1@v, t2 = a2@v, u = silu(t1)*t2 ----------------
// grid (32 t-tiles, 24 bh). 256 thr = 4 waves x 16 t-rows.
__global__ __launch_bounds__(256) void pass1(const unsigned short* __restrict__ qkv,
                                             const unsigned short* __restrict__ vt,
                                             unsigned short* __restrict__ u) {
  __shared__ __align__(16) char smem[40960];
  char* K1s = smem;           // [64 s][64 d] bf16 swizzled
  char* K2s = smem + 8192;
  char* Vts = smem + 16384;   // [64 d][64 s] bf16 swizzled (from vt global)
  char* A1s = smem + 24576;   // 4 waves x [16 t][64 s] bf16 swizzled
  char* A2s = smem + 32768;
  const int tid = threadIdx.x, w = tid >> 6, l = tid & 63;
  const int tt = blockIdx.x;
  const int bh = blockIdx.y;
  const int b = bh / 12, h = bh % 12;

  // preload Q1/Q2 fragments (A-operand): row = l&15, k contiguous
  const int tg = tt * 64 + w * 16 + (l & 15);
  const size_t qbase = (size_t)(b * 2048 + tg) * 5376 + h * 64;
  short8 q1f[2], q2f[2];
  for (int kc = 0; kc < 2; ++kc) {
    int d = kc * 32 + (l >> 4) * 8;
    q1f[kc] = *(const short8*)(qkv + qbase + 0 * 768 + d);
    q2f[kc] = *(const short8*)(qkv + qbase + 2 * 768 + d);
  }

  f32x4 z; z.x = 0.f; z.y = 0.f; z.z = 0.f; z.w = 0.f;
  f32x4 t1a[4], t2a[4];
  for (int n = 0; n < 4; ++n) { t1a[n] = z; t2a[n] = z; }

  for (int s0 = 0; s0 < 2048; s0 += 64) {
    // stage K1, K2 (row-major swizzled) + Vt tile, all via global_load_lds
    for (int it = 0; it < 2; ++it) {
      int slot = it * 256 + tid;          // 512 slots per tile
      int row = slot >> 3, j = slot & 7;
      int gc = j ^ (row & 7);
      const unsigned short* k1src = qkv + (size_t)(b * 2048 + s0 + row) * 5376 + h * 64 + 768 + gc * 8;
      GLOAD16(k1src, K1s + slot * 16);
      GLOAD16(k1src + 2 * 768, K2s + slot * 16);
      GLOAD16(vt + (size_t)(bh * 64 + row) * 2048 + s0 + gc * 8, Vts + slot * 16);
    }
    __syncthreads();

    // scores: a1,a2 = Q K^T  (16 t-rows x 64 s-cols per wave)
    f32x4 a1[4], a2[4];
    for (int n = 0; n < 4; ++n) { a1[n] = z; a2[n] = z; }
    for (int kc = 0; kc < 2; ++kc) {
      int c = (l >> 4) + 4 * kc;
      for (int n = 0; n < 4; ++n) {
        int srw = n * 16 + (l & 15);
        short8 k1f = *(const short8*)(K1s + srw * 128 + ((c ^ (srw & 7)) * 16));
        short8 k2f = *(const short8*)(K2s + srw * 128 + ((c ^ (srw & 7)) * 16));
        a1[n] = MFMA16(q1f[kc], k1f, a1[n], 0, 0, 0);
        a2[n] = MFMA16(q2f[kc], k2f, a2[n], 0, 0, 0);
      }
    }

    // write scores to per-wave LDS (bf16) to re-fragment for PV
    char* myA1 = A1s + w * 2048;
    char* myA2 = A2s + w * 2048;
    for (int n = 0; n < 4; ++n)
      for (int r = 0; r < 4; ++r) {
        int trow = (l >> 4) * 4 + r;
        int scol = n * 16 + (l & 15);
        int byte = trow * 128 + (((scol >> 3) ^ (trow & 7)) * 16) + (scol & 7) * 2;
        *(unsigned short*)(myA1 + byte) = f2bf(a1[n][r]);
        *(unsigned short*)(myA2 + byte) = f2bf(a2[n][r]);
      }
    __syncthreads();

    // PV: t1 += a1 @ V, t2 += a2 @ V  (k = s)
    for (int kc = 0; kc < 2; ++kc) {
      int trow = l & 15;
      int c = (l >> 4) + 4 * kc;
      short8 p1 = *(const short8*)(myA1 + trow * 128 + ((c ^ (trow & 7)) * 16));
      short8 p2 = *(const short8*)(myA2 + trow * 128 + ((c ^ (trow & 7)) * 16));
      for (int n = 0; n < 4; ++n) {
        int drow = n * 16 + (l & 15);
        short8 vf = *(const short8*)(Vts + drow * 128 + ((c ^ (drow & 7)) * 16));
        t1a[n] = MFMA16(p1, vf, t1a[n], 0, 0, 0);
        t2a[n] = MFMA16(p2, vf, t2a[n], 0, 0, 0);
      }
    }
    __syncthreads();
  }

  // u = silu(t1) * t2, store bf16 [b][t][h*64+d]
  for (int n = 0; n < 4; ++n)
    for (int r = 0; r < 4; ++r) {
      int t = tt * 64 + w * 16 + (l >> 4) * 4 + r;
      int d = n * 16 + (l & 15);
      float x1 = t1a[n][r], x2 = t2a[n][r];
      float uu = (x1 / (1.f + expf(-x1))) * x2;
      u[(size_t)(b * 2048 + t) * 768 + h * 64 + d] = f2bf(uu);
    }
}

// ---------------- pass2: ctx = a3 @ u, + per-block GN partial sums ----------------
__global__ __launch_bounds__(256) void pass2(const unsigned short* __restrict__ qkv,
                                             const unsigned short* __restrict__ ut,
                                             float* __restrict__ ctx,
                                             float* __restrict__ partials) {
  __shared__ __align__(16) char smem[24576];
  char* K3s = smem;           // [64 s][64 d]
  char* Uts = smem + 8192;    // [64 d][64 s] (from ut global)
  char* A3s = smem + 16384;   // 4 x [16][64]
  const int tid = threadIdx.x, w = tid >> 6, l = tid & 63;
  const int tt = blockIdx.x;
  const int bh = blockIdx.y;
  const int b = bh / 12, h = bh % 12;

  const int tg = tt * 64 + w * 16 + (l & 15);
  const size_t qbase = (size_t)(b * 2048 + tg) * 5376 + h * 64;
  short8 q3f[2];
  for (int kc = 0; kc < 2; ++kc)
    q3f[kc] = *(const short8*)(qkv + qbase + 4 * 768 + kc * 32 + (l >> 4) * 8);

  f32x4 z; z.x = 0.f; z.y = 0.f; z.z = 0.f; z.w = 0.f;
  f32x4 ca[4];
  for (int n = 0; n < 4; ++n) ca[n] = z;

  for (int s0 = 0; s0 < 2048; s0 += 64) {
    for (int it = 0; it < 2; ++it) {
      int slot = it * 256 + tid;
      int row = slot >> 3, j = slot & 7;
      int gc = j ^ (row & 7);
      GLOAD16(qkv + (size_t)(b * 2048 + s0 + row) * 5376 + h * 64 + 5 * 768 + gc * 8,
              K3s + slot * 16);
      GLOAD16(ut + (size_t)(bh * 64 + row) * 2048 + s0 + gc * 8, Uts + slot * 16);
    }
    __syncthreads();

    f32x4 a3[4];
    for (int n = 0; n < 4; ++n) a3[n] = z;
    for (int kc = 0; kc < 2; ++kc) {
      int c = (l >> 4) + 4 * kc;
      for (int n = 0; n < 4; ++n) {
        int srw = n * 16 + (l & 15);
        short8 kf = *(const short8*)(K3s + srw * 128 + ((c ^ (srw & 7)) * 16));
        a3[n] = MFMA16(q3f[kc], kf, a3[n], 0, 0, 0);
      }
    }
    char* myA = A3s + w * 2048;
    for (int n = 0; n < 4; ++n)
      for (int r = 0; r < 4; ++r) {
        int trow = (l >> 4) * 4 + r;
        int scol = n * 16 + (l & 15);
        int byte = trow * 128 + (((scol >> 3) ^ (trow & 7)) * 16) + (scol & 7) * 2;
        *(unsigned short*)(myA + byte) = f2bf(a3[n][r]);
      }
    __syncthreads();

    for (int kc = 0; kc < 2; ++kc) {
      int trow = l & 15;
      int c = (l >> 4) + 4 * kc;
      short8 p3 = *(const short8*)(myA + trow * 128 + ((c ^ (trow & 7)) * 16));
      for (int n = 0; n < 4; ++n) {
        int drow = n * 16 + (l & 15);
        short8 uf = *(const short8*)(Uts + drow * 128 + ((c ^ (drow & 7)) * 16));
        ca[n] = MFMA16(p3, uf, ca[n], 0, 0, 0);
      }
    }
    __syncthreads();
  }

  float psum = 0.f, psum2 = 0.f;
  for (int n = 0; n < 4; ++n)
    for (int r = 0; r < 4; ++r) {
      int t = tt * 64 + w * 16 + (l >> 4) * 4 + r;
      int d = n * 16 + (l & 15);
      float v = ca[n][r];
      ctx[(size_t)(b * 2048 + t) * 768 + h * 64 + d] = v;
      psum += v; psum2 += v * v;
    }

  // block-level reduce of (sum, sumsq) -> partials[(bh*32+tt)*2 .. +1]
  float* red = (float*)smem;                  // reuse LDS (done with tiles)
  red[tid] = psum; red[256 + tid] = psum2;
  __syncthreads();
  for (int st = 128; st > 0; st >>= 1) {
    if (tid < st) {
      red[tid] += red[tid + st];
      red[256 + tid] += red[256 + tid + st];
    }
    __syncthreads();
  }
  if (tid == 0) {
    partials[(bh * 32 + tt) * 2] = red[0];
    partials[(bh * 32 + tt) * 2 + 1] = red[256];
  }
}

// ---------------- finalize GN stats from 32 partials per group ----------------
__global__ __launch_bounds__(64) void gn_finalize(const float* __restrict__ partials,
                                                  float* __restrict__ stats) {
  const int g = blockIdx.x;      // 0..23
  const int l = threadIdx.x;     // 0..63
  double s = 0.0, s2 = 0.0;
  if (l < 32) {
    s = (double)partials[(g * 32 + l) * 2];
    s2 = (double)partials[(g * 32 + l) * 2 + 1];
  }
  for (int off = 32; off > 0; off >>= 1) {
    s += __shfl_down(s, off, 64);
    s2 += __shfl_down(s2, off, 64);
  }
  if (l == 0) {
    const double N = 2048.0 * 64.0;
    double mean = s / N;
    double var = s2 / N - mean * mean;
    stats[g * 2] = (float)mean;
    stats[g * 2 + 1] = (float)(1.0 / sqrt(var + 1e-5));
  }
}

// ---------------- normalize + affine -> bf16 ----------------
__global__ __launch_bounds__(256) void gn_apply(const float* __restrict__ ctx,
                                                const float* __restrict__ stats,
                                                const float* __restrict__ gw,
                                                const float* __restrict__ gb,
                                                unsigned short* __restrict__ outc) {
  int i = blockIdx.x * 256 + threadIdx.x;
  if (i >= 4096 * 768) return;
  int c = i % 768;
  int b = i / (2048 * 768);
  int g = b * 12 + (c >> 6);
  float v = (ctx[i] - stats[2 * g]) * stats[2 * g + 1];
  outc[i] = f2bf(v * gw[c] + gb[c]);
}

extern "C" void kernel_launch(void* const* d_in, const int* in_sizes, int n_in,
                              void* d_out, int out_size, void* d_ws, size_t ws_size,
                              hipStream_t stream) {
  const float* x   = (const float*)d_in[0];
  const float* Wpw = (const float*)d_in[1];
  const float* Wpb = (const float*)d_in[2];
  const float* gnw = (const float*)d_in[3];
  const float* gnb = (const float*)d_in[4];
  const float* ow  = (const float*)d_in[5];
  const float* ob  = (const float*)d_in[6];
  float* out = (float*)d_out;

  char* ws = (char*)d_ws;
  size_t off = 0;
  auto carve = [&](size_t bytes) {
    char* p = ws + off;
    off = (off + bytes + 255) & ~(size_t)255;
    return p;
  };
  unsigned short* xb   = (unsigned short*)carve((size_t)4096 * 768 * 2);   // x bf16; reused as ctxn
  unsigned short* wb   = (unsigned short*)carve((size_t)5376 * 768 * 2);   // Wproj bf16
  unsigned short* owb  = (unsigned short*)carve((size_t)768 * 768 * 2);    // out_w bf16
  unsigned short* qkvb = (unsigned short*)carve((size_t)4096 * 5376 * 2);  // qkv bf16
  unsigned short* ub   = (unsigned short*)carve((size_t)4096 * 768 * 2);   // u bf16
  unsigned short* vtb  = (unsigned short*)carve((size_t)24 * 64 * 2048 * 2); // V^T [bh][d][s]
  unsigned short* utb  = (unsigned short*)carve((size_t)24 * 64 * 2048 * 2); // u^T [bh][d][s]
  float* ctx           = (float*)carve((size_t)4096 * 768 * 4);            // ctx f32
  float* partials      = (float*)carve(24 * 32 * 2 * 4);                   // per-block GN sums
  float* stats         = (float*)carve(48 * 4);                            // mean/rstd x24

  cvt_bf16_4<<<3072, 256, 0, stream>>>(x, xb, 4096 * 768);
  cvt_bf16_4<<<4032, 256, 0, stream>>>(Wpw, wb, 5376 * 768);
  cvt_bf16_4<<<576, 256, 0, stream>>>(ow, owb, 768 * 768);

  gemm_nt<true><<<dim3(42, 32), 256, 0, stream>>>(xb, wb, Wpb, qkvb, 4096, 5376, 768);
  transp64<<<dim3(32, 24), 256, 0, stream>>>(qkvb, 5376, 6 * 768, vtb);   // V -> V^T
  pass1<<<dim3(32, 24), 256, 0, stream>>>(qkvb, vtb, ub);
  transp64<<<dim3(32, 24), 256, 0, stream>>>(ub, 768, 0, utb);            // u -> u^T
  pass2<<<dim3(32, 24), 256, 0, stream>>>(qkvb, utb, ctx, partials);
  gn_finalize<<<24, 64, 0, stream>>>(partials, stats);
  gn_apply<<<12288, 256, 0, stream>>>(ctx, stats, gnw, gnb, xb);  // xb reused as ctxn
  gemm_nt<false><<<dim3(6, 32), 256, 0, stream>>>(xb, owb, ob, out, 4096, 768, 768);
}